// Round 1
// baseline (191.143 us; speedup 1.0000x reference)
//
#include <hip/hip_runtime.h>
#include <hip/hip_bf16.h>
#include <cstdint>
#include <cstddef>

// ---------- constants (problem sizes) ----------
#define B_  8
#define M_  256
#define E_  128
#define K_  16
#define H_  1024
#define A_  256
#define R_  1024
#define RMS_ 512
#define NEG_ (-1e25f)

typedef __bf16 bf16x8 __attribute__((ext_vector_type(8)));
typedef float  f32x4  __attribute__((ext_vector_type(4)));
typedef short  s16x8  __attribute__((ext_vector_type(8)));

__device__ __forceinline__ short f2bf(float f) {
  union { float f; unsigned u; } v; v.f = f;
  unsigned r = v.u + 0x7fffu + ((v.u >> 16) & 1u);  // RNE
  return (short)(r >> 16);
}

// ---------- prep: cast everything to bf16 (+ rm transpose) ----------
__global__ __launch_bounds__(256) void prep_cast(
    const float* __restrict__ X, const float* __restrict__ Wv,
    const float* __restrict__ Wu, const float* __restrict__ Wr,
    const float* __restrict__ Wo, const float* __restrict__ rm,
    short* __restrict__ Xb, short* __restrict__ Wvb, short* __restrict__ Wub,
    short* __restrict__ Wrb, short* __restrict__ Wob,
    short* __restrict__ rmb, short* __restrict__ rmTb) {
  const long NX = 2048 * 1024, NWV = 256 * 1024, NWR = 1024 * 512,
             NWO = 1024 * 1536, NRM = 1024 * 512;
  long i = (long)blockIdx.x * 256 + threadIdx.x;
  if (i < NX) { Xb[i] = f2bf(X[i]); return; } i -= NX;
  if (i < NWV) { Wvb[i] = f2bf(Wv[i]); return; } i -= NWV;
  if (i < NWV) { Wub[i] = f2bf(Wu[i]); return; } i -= NWV;
  if (i < NWR) { Wrb[i] = f2bf(Wr[i]); return; } i -= NWR;
  if (i < NWO) { Wob[i] = f2bf(Wo[i]); return; } i -= NWO;
  if (i < NRM) {
    short v = f2bf(rm[i]); rmb[i] = v;
    int r = (int)(i >> 9), c = (int)(i & 511);
    rmTb[(long)c * 1024 + r] = v;
  }
}

// ---------- fused V/U projection GEMM: P = tanh(X Wv^T + bv) * sigmoid(X Wu^T + bu) ----------
// M=2048, N=256, K=1024. Block tile 32x64, 4 waves (2m x 2n), wave tile 16x32.
__global__ __launch_bounds__(256) void gemm_vu(
    const short* __restrict__ A, const short* __restrict__ Bv,
    const short* __restrict__ Bu, const float* __restrict__ bv,
    const float* __restrict__ bu, float* __restrict__ P) {
  constexpr int BM = 32, BN = 64;
  __shared__ alignas(16) short As[BM][40];
  __shared__ alignas(16) short Bvs[BN][40];
  __shared__ alignas(16) short Bus[BN][40];
  const int tid = threadIdx.x;
  const int wave = tid >> 6, lane = tid & 63;
  const int quad = lane >> 4, l16 = lane & 15;
  const int wm = (wave & 1) * 16, wn = (wave >> 1) * 32;
  const int m0 = blockIdx.x * BM, n0 = blockIdx.y * BN;

  f32x4 accv[2] = {}, accu[2] = {};
  for (int k0 = 0; k0 < H_; k0 += 32) {
    for (int c = tid; c < BM * 4; c += 256) {
      int r = c >> 2, kc = (c & 3) * 8;
      *(s16x8*)&As[r][kc] = *(const s16x8*)&A[(long)(m0 + r) * H_ + k0 + kc];
    }
    for (int c = tid; c < BN * 4; c += 256) {
      int r = c >> 2, kc = (c & 3) * 8;
      *(s16x8*)&Bvs[r][kc] = *(const s16x8*)&Bv[(long)(n0 + r) * H_ + k0 + kc];
      *(s16x8*)&Bus[r][kc] = *(const s16x8*)&Bu[(long)(n0 + r) * H_ + k0 + kc];
    }
    __syncthreads();
    bf16x8 af = *(const bf16x8*)&As[wm + l16][quad * 8];
    #pragma unroll
    for (int j = 0; j < 2; ++j) {
      bf16x8 bfv = *(const bf16x8*)&Bvs[wn + j * 16 + l16][quad * 8];
      bf16x8 bfu = *(const bf16x8*)&Bus[wn + j * 16 + l16][quad * 8];
      accv[j] = __builtin_amdgcn_mfma_f32_16x16x32_bf16(af, bfv, accv[j], 0, 0, 0);
      accu[j] = __builtin_amdgcn_mfma_f32_16x16x32_bf16(af, bfu, accu[j], 0, 0, 0);
    }
    __syncthreads();
  }
  #pragma unroll
  for (int j = 0; j < 2; ++j) {
    int col = n0 + wn + j * 16 + l16;
    float bvc = bv[col], buc = bu[col];
    #pragma unroll
    for (int r = 0; r < 4; ++r) {
      int row = m0 + wm + quad * 4 + r;
      float v = tanhf(accv[j][r] + bvc);
      float u = accu[j][r] + buc;
      float su = 1.0f / (1.0f + expf(-u));
      P[(long)row * A_ + col] = v * su;
    }
  }
}

// ---------- w = P @ Wa + ba ----------
__global__ __launch_bounds__(256) void w_reduce(
    const float* __restrict__ P, const float* __restrict__ Wa,
    const float* __restrict__ ba, float* __restrict__ w) {
  int row = blockIdx.x * 4 + (threadIdx.x >> 6);
  int lane = threadIdx.x & 63;
  float4 p = *(const float4*)&P[(long)row * A_ + lane * 4];
  float4 a = *(const float4*)&Wa[lane * 4];
  float s = p.x * a.x + p.y * a.y + p.z * a.z + p.w * a.w;
  #pragma unroll
  for (int off = 32; off > 0; off >>= 1) s += __shfl_down(s, off);
  if (lane == 0) w[row] = s + ba[0];
}

// ---------- masked softmax over K + weighted pooling -> cat[:, 0:H] (bf16) ----------
__global__ __launch_bounds__(256) void softmax_pool(
    const float* __restrict__ ment, const int* __restrict__ ents,
    const int* __restrict__ msk, const float* __restrict__ w,
    short* __restrict__ catb) {
  __shared__ float a_sh[K_];
  __shared__ int idx_sh[K_];
  const int be = blockIdx.x;
  const int b = be >> 7;  // E=128
  const int tid = threadIdx.x;
  if (tid < K_) {
    int idx = ents[be * K_ + tid];
    int mk = msk[be * K_ + tid];
    idx_sh[tid] = idx;
    a_sh[tid] = mk ? w[(b << 8) + idx] : NEG_;
  }
  __syncthreads();
  if (tid == 0) {
    float mx = a_sh[0];
    #pragma unroll
    for (int k = 1; k < K_; ++k) mx = fmaxf(mx, a_sh[k]);
    float e[K_]; float s = 0.f;
    #pragma unroll
    for (int k = 0; k < K_; ++k) { e[k] = expf(a_sh[k] - mx); s += e[k]; }
    float inv = 1.0f / s;
    #pragma unroll
    for (int k = 0; k < K_; ++k) a_sh[k] = e[k] * inv;
  }
  __syncthreads();
  const float* Xb = ment + ((long)b << 18);  // b*M*H
  const int h0 = tid * 4;
  float ax = 0.f, ay = 0.f, az = 0.f, aw = 0.f;
  #pragma unroll
  for (int k = 0; k < K_; ++k) {
    float ak = a_sh[k];
    float4 xv = *(const float4*)&Xb[(long)idx_sh[k] * H_ + h0];
    ax += ak * xv.x; ay += ak * xv.y; az += ak * xv.z; aw += ak * xv.w;
  }
  short* crow = catb + (long)be * (H_ + RMS_) + h0;
  crow[0] = f2bf(ax); crow[1] = f2bf(ay); crow[2] = f2bf(az); crow[3] = f2bf(aw);
}

// ---------- generic GEMM: C[M,N] = A[M,K] @ B[N,K]^T (+bias) ----------
// EPI 0: bf16 store (bias optional), EPI 1: f32 store + bias
template <int BM, int BN, int EPI>
__global__ __launch_bounds__(256) void gemm_bt(
    const short* __restrict__ A, int lda, const short* __restrict__ B, int ldb,
    const float* __restrict__ bias, void* __restrict__ C, int ldc, int K) {
  constexpr int WM = BM / 2, WN = BN / 2, FM = WM / 16, FN = WN / 16;
  __shared__ alignas(16) short As[BM][40];
  __shared__ alignas(16) short Bs[BN][40];
  const int tid = threadIdx.x;
  const int wave = tid >> 6, lane = tid & 63;
  const int quad = lane >> 4, l16 = lane & 15;
  const int wm = (wave & 1) * WM, wn = (wave >> 1) * WN;
  const int m0 = blockIdx.x * BM, n0 = blockIdx.y * BN;

  f32x4 acc[FM][FN] = {};
  for (int k0 = 0; k0 < K; k0 += 32) {
    for (int c = tid; c < BM * 4; c += 256) {
      int r = c >> 2, kc = (c & 3) * 8;
      *(s16x8*)&As[r][kc] = *(const s16x8*)&A[(long)(m0 + r) * lda + k0 + kc];
    }
    for (int c = tid; c < BN * 4; c += 256) {
      int r = c >> 2, kc = (c & 3) * 8;
      *(s16x8*)&Bs[r][kc] = *(const s16x8*)&B[(long)(n0 + r) * ldb + k0 + kc];
    }
    __syncthreads();
    bf16x8 af[FM], bfr[FN];
    #pragma unroll
    for (int i = 0; i < FM; ++i) af[i] = *(const bf16x8*)&As[wm + i * 16 + l16][quad * 8];
    #pragma unroll
    for (int j = 0; j < FN; ++j) bfr[j] = *(const bf16x8*)&Bs[wn + j * 16 + l16][quad * 8];
    #pragma unroll
    for (int i = 0; i < FM; ++i)
      #pragma unroll
      for (int j = 0; j < FN; ++j)
        acc[i][j] = __builtin_amdgcn_mfma_f32_16x16x32_bf16(af[i], bfr[j], acc[i][j], 0, 0, 0);
    __syncthreads();
  }
  #pragma unroll
  for (int i = 0; i < FM; ++i)
    #pragma unroll
    for (int j = 0; j < FN; ++j) {
      int col = n0 + wn + j * 16 + l16;
      float bc = bias ? bias[col] : 0.f;
      #pragma unroll
      for (int r = 0; r < 4; ++r) {
        int row = m0 + wm + i * 16 + quad * 4 + r;
        float v = acc[i][j][r] + bc;
        if (EPI == 0) ((short*)C)[(long)row * ldc + col] = f2bf(v);
        else          ((float*)C)[(long)row * ldc + col] = v;
      }
    }
}

extern "C" void kernel_launch(void* const* d_in, const int* in_sizes, int n_in,
                              void* d_out, int out_size, void* d_ws, size_t ws_size,
                              hipStream_t stream) {
  const float* ment = (const float*)d_in[0];
  const int*   ents = (const int*)d_in[1];
  const int*   msk  = (const int*)d_in[2];
  const float* rm   = (const float*)d_in[3];
  const float* Wv   = (const float*)d_in[4];
  const float* bv   = (const float*)d_in[5];
  const float* Wu   = (const float*)d_in[6];
  const float* bu   = (const float*)d_in[7];
  const float* Wa   = (const float*)d_in[8];
  const float* ba   = (const float*)d_in[9];
  const float* Wr   = (const float*)d_in[10];
  const float* br   = (const float*)d_in[11];
  const float* Wo   = (const float*)d_in[12];
  const float* bo   = (const float*)d_in[13];
  float* out = (float*)d_out;

  char* p = (char*)d_ws;
  auto alloc = [&](size_t bytes) { void* q = (void*)p; p += bytes; return q; };
  short* Xb   = (short*)alloc((size_t)2048 * 1024 * 2);   // bf16 mentions [B*M, H]
  short* Wvb  = (short*)alloc((size_t)256 * 1024 * 2);
  short* Wub  = (short*)alloc((size_t)256 * 1024 * 2);
  short* Wrb  = (short*)alloc((size_t)1024 * 512 * 2);
  short* Wob  = (short*)alloc((size_t)1024 * 1536 * 2);
  short* rmb  = (short*)alloc((size_t)1024 * 512 * 2);    // [R, RMS]
  short* rmTb = (short*)alloc((size_t)512 * 1024 * 2);    // [RMS, R]
  short* swb  = (short*)alloc((size_t)1024 * 1024 * 2);   // s_w bf16 [R, H]
  short* sb   = (short*)alloc((size_t)1024 * 1024 * 2);   // s bf16 [BE, R]
  short* catb = (short*)alloc((size_t)1024 * 1536 * 2);   // [BE, H+RMS]
  float* P    = (float*)alloc((size_t)2048 * 256 * 4);    // VU gate product
  float* w    = (float*)alloc((size_t)2048 * 4);          // per-mention logit

  // 1. casts
  prep_cast<<<20480, 256, 0, stream>>>(ment, Wv, Wu, Wr, Wo, rm,
                                       Xb, Wvb, Wub, Wrb, Wob, rmb, rmTb);
  // 2. P = tanh(X Wv^T + bv) * sigmoid(X Wu^T + bu)   [2048, 256]
  gemm_vu<<<dim3(64, 4), 256, 0, stream>>>(Xb, Wvb, Wub, bv, bu, P);
  // 3. w = P @ Wa + ba   [2048]
  w_reduce<<<512, 256, 0, stream>>>(P, Wa, ba, w);
  // 4. s_w = rm @ Wr^T + br  -> bf16 [R=1024, H=1024], K=512
  gemm_bt<64, 64, 0><<<dim3(16, 16), 256, 0, stream>>>(rmb, 512, Wrb, 512, br, swb, 1024, 512);
  // 5. softmax over K + pooling -> cat[:, 0:1024]
  softmax_pool<<<1024, 256, 0, stream>>>(ment, ents, msk, w, catb);
  // 6. s = er @ s_w^T  [1024, 1024], K=1024  (A rows = cat rows, lda=1536)
  gemm_bt<64, 64, 0><<<dim3(16, 16), 256, 0, stream>>>(catb, 1536, swb, 1024, nullptr, sb, 1024, 1024);
  // 7. s2 = s @ rm  [1024, 512], K=1024 -> cat[:, 1024:1536]
  gemm_bt<64, 32, 0><<<dim3(16, 16), 256, 0, stream>>>(sb, 1024, rmTb, 1024, nullptr, catb + 1024, 1536, 1024);
  // 8. out = cat @ Wo^T + bo  [1024, 1024], K=1536, fp32
  gemm_bt<64, 64, 1><<<dim3(16, 16), 256, 0, stream>>>(catb, 1536, Wob, 1536, bo, out, 1024, 1536);
}

// Round 2
// 186.700 us; speedup vs baseline: 1.0238x; 1.0238x over previous
//
#include <hip/hip_runtime.h>
#include <hip/hip_bf16.h>
#include <cstdint>
#include <cstddef>

#define NEG_ (-1e25f)

typedef __bf16 bf16x8 __attribute__((ext_vector_type(8)));
typedef float  f32x4  __attribute__((ext_vector_type(4)));

typedef const __attribute__((address_space(1))) void* gas_t;
typedef __attribute__((address_space(3))) void* las_t;

__device__ __forceinline__ short f2bf(float f) {
  union { float f; unsigned u; } v; v.f = f;
  unsigned r = v.u + 0x7fffu + ((v.u >> 16) & 1u);  // RNE
  return (short)(r >> 16);
}

// ---------------- prep: casts, transposes, augmentation, zero-init ----------------
// Xb[2048,1024], Wvb[256,1024], Wub[256,1024], WrTb[512,1024],
// WoFb[1024,1568] (cols 0:1024 = Wo1; 1536:1568 zeroed), Wo2b[1024,512],
// rmTaug[576,1024] (rows 0:512 = rm^T, row 512 = ones), w[2048] = 0
__global__ __launch_bounds__(256) void prep_cast(
    const float* __restrict__ X, const float* __restrict__ Wv,
    const float* __restrict__ Wu, const float* __restrict__ Wr,
    const float* __restrict__ Wo, const float* __restrict__ rm,
    short* __restrict__ Xb, short* __restrict__ Wvb, short* __restrict__ Wub,
    short* __restrict__ WrTb, short* __restrict__ WoFb, short* __restrict__ Wo2b,
    short* __restrict__ rmTaug, float* __restrict__ w) {
  long i = (long)blockIdx.x * 256 + threadIdx.x;
  if (i < 2097152) { Xb[i] = f2bf(X[i]); return; } i -= 2097152;
  if (i < 262144) { Wvb[i] = f2bf(Wv[i]); return; } i -= 262144;
  if (i < 262144) { Wub[i] = f2bf(Wu[i]); return; } i -= 262144;
  if (i < 524288) {  // Wr [1024,512] -> WrT [512,1024]
    int h = (int)(i >> 9), m = (int)(i & 511);
    WrTb[(long)m * 1024 + h] = f2bf(Wr[i]); return; } i -= 524288;
  if (i < 1572864) {  // Wo [1024,1536] split
    int h = (int)(i / 1536), col = (int)(i - (long)h * 1536);
    short v = f2bf(Wo[i]);
    if (col < 1024) WoFb[(long)h * 1568 + col] = v;
    else            Wo2b[(long)h * 512 + (col - 1024)] = v;
    return; } i -= 1572864;
  if (i < 32768) {  // zero WoFb cols 1536..1567 (col 1536 later overwritten by GWT)
    int h = (int)(i >> 5), z = (int)(i & 31);
    WoFb[(long)h * 1568 + 1536 + z] = 0; return; } i -= 32768;
  if (i < 524288) {  // rm [1024,512] -> rmT [512,1024]
    int r = (int)(i >> 9), m = (int)(i & 511);
    rmTaug[(long)m * 1024 + r] = f2bf(rm[i]); return; } i -= 524288;
  if (i < 1024) { rmTaug[(long)512 * 1024 + i] = (short)0x3F80; return; } i -= 1024;
  if (i < 2048) { w[i] = 0.f; }
}

// ---------------- fused V/U gate GEMM + w reduction ----------------
// per-mention: w[row] += sum_col tanh(X Wv^T + bv)*sigmoid(X Wu^T + bu) * Wa[col]
// M=2048, N=256 (4 col-blocks of 64), K=1024. Tile 32x64, 4 waves, PD=3 pipeline.
__global__ __launch_bounds__(256) void gemm_vu_w(
    const short* __restrict__ Aq, const short* __restrict__ Bv,
    const short* __restrict__ Bu, const float* __restrict__ bv,
    const float* __restrict__ bu, const float* __restrict__ Wa,
    float* __restrict__ w) {
  constexpr int PD = 3;
  __shared__ alignas(16) short As[PD][32 * 32];
  __shared__ alignas(16) short Bs[PD][128 * 32];  // rows 0:64 Bv, 64:128 Bu
  const int tid = threadIdx.x;
  const int wave = tid >> 6, lane = tid & 63;
  const int quad = lane >> 4, l16 = lane & 15;
  const int wm = (wave & 1) * 16, wn = (wave >> 1) * 32;
  const int m0 = blockIdx.x * 32, n0 = blockIdx.y * 64;
  const int aseg = tid & 127;                    // A duplicated across halves
  const int arow = aseg >> 2, acol = (aseg & 3) * 8;
  const int brow = tid >> 2, bcol = (tid & 3) * 8;
  const short* Agp = Aq + (long)(m0 + arow) * 1024 + acol;
  const short* Bvp = Bv + (long)(n0 + brow) * 1024 + bcol;
  const short* Bup = Bu + (long)(n0 + brow) * 1024 + bcol;
  const int aoff  = (wave & 1) * 16 * 32;        // wave-uniform LDS bases
  const int bvoff = wave * 16 * 32;
  const int buoff = (64 + wave * 16) * 32;
  f32x4 accv[2] = {}, accu[2] = {};
  const int NT = 32;
  auto issue = [&](int kt) {
    int buf = kt % PD; int ko = kt * 32;
    __builtin_amdgcn_global_load_lds((gas_t)(Agp + ko), (las_t)(As[buf] + aoff), 16, 0, 0);
    __builtin_amdgcn_global_load_lds((gas_t)(Bvp + ko), (las_t)(Bs[buf] + bvoff), 16, 0, 0);
    __builtin_amdgcn_global_load_lds((gas_t)(Bup + ko), (las_t)(Bs[buf] + buoff), 16, 0, 0);
  };
  issue(0); issue(1);
  for (int kt = 0; kt < NT; ++kt) {
    if (kt + 2 < NT) issue(kt + 2);
    int ahead = NT - 1 - kt; if (ahead > 2) ahead = 2;
    if (ahead == 2)      asm volatile("s_waitcnt vmcnt(6)" ::: "memory");
    else if (ahead == 1) asm volatile("s_waitcnt vmcnt(3)" ::: "memory");
    else                 asm volatile("s_waitcnt vmcnt(0)" ::: "memory");
    asm volatile("s_barrier" ::: "memory");
    const short* as = As[kt % PD];
    const short* bs = Bs[kt % PD];
    bf16x8 af = *(const bf16x8*)&as[(wm + l16) * 32 + quad * 8];
    #pragma unroll
    for (int j = 0; j < 2; ++j) {
      bf16x8 bfv = *(const bf16x8*)&bs[(wn + j * 16 + l16) * 32 + quad * 8];
      bf16x8 bfu = *(const bf16x8*)&bs[(64 + wn + j * 16 + l16) * 32 + quad * 8];
      accv[j] = __builtin_amdgcn_mfma_f32_16x16x32_bf16(af, bfv, accv[j], 0, 0, 0);
      accu[j] = __builtin_amdgcn_mfma_f32_16x16x32_bf16(af, bfu, accu[j], 0, 0, 0);
    }
    asm volatile("s_barrier" ::: "memory");
  }
  float wsum[4] = {0.f, 0.f, 0.f, 0.f};
  #pragma unroll
  for (int j = 0; j < 2; ++j) {
    int col = n0 + wn + j * 16 + l16;
    float bvc = bv[col], buc = bu[col], wac = Wa[col];
    #pragma unroll
    for (int r = 0; r < 4; ++r) {
      float vv = tanhf(accv[j][r] + bvc);
      float uu = accu[j][r] + buc;
      float gate = vv / (1.0f + expf(-uu));
      wsum[r] += gate * wac;
    }
  }
  #pragma unroll
  for (int r = 0; r < 4; ++r) {
    float s = wsum[r];
    s += __shfl_down(s, 8, 16);
    s += __shfl_down(s, 4, 16);
    s += __shfl_down(s, 2, 16);
    s += __shfl_down(s, 1, 16);
    if (l16 == 0) atomicAdd(&w[m0 + wm + quad * 4 + r], s);
  }
}

// ---------------- masked softmax + pooling -> er, c, zero pad ----------------
__global__ __launch_bounds__(256) void softmax_pool(
    const float* __restrict__ ment, const int* __restrict__ ents,
    const int* __restrict__ msk, const float* __restrict__ w,
    const float* __restrict__ br, short* __restrict__ catb) {
  __shared__ float a_sh[16];
  __shared__ int idx_sh[16];
  __shared__ float csum[4];
  const int be = blockIdx.x;
  const int b = be >> 7;  // E=128
  const int tid = threadIdx.x;
  if (tid < 16) {
    int idx = ents[be * 16 + tid];
    int mk = msk[be * 16 + tid];
    idx_sh[tid] = idx;
    a_sh[tid] = mk ? w[(b << 8) + idx] : NEG_;
  }
  __syncthreads();
  if (tid == 0) {
    float mx = a_sh[0];
    #pragma unroll
    for (int k = 1; k < 16; ++k) mx = fmaxf(mx, a_sh[k]);
    float e[16]; float s = 0.f;
    #pragma unroll
    for (int k = 0; k < 16; ++k) { e[k] = expf(a_sh[k] - mx); s += e[k]; }
    float inv = 1.0f / s;
    #pragma unroll
    for (int k = 0; k < 16; ++k) a_sh[k] = e[k] * inv;
  }
  __syncthreads();
  const float* Xb = ment + ((long)b << 18);
  const int h0 = tid * 4;
  float ax = 0.f, ay = 0.f, az = 0.f, aw = 0.f;
  #pragma unroll
  for (int k = 0; k < 16; ++k) {
    float ak = a_sh[k];
    float4 xv = *(const float4*)&Xb[(long)idx_sh[k] * 1024 + h0];
    ax += ak * xv.x; ay += ak * xv.y; az += ak * xv.z; aw += ak * xv.w;
  }
  short* crow = catb + (long)be * 1568;
  crow[h0] = f2bf(ax); crow[h0 + 1] = f2bf(ay);
  crow[h0 + 2] = f2bf(az); crow[h0 + 3] = f2bf(aw);
  float4 brv = *(const float4*)&br[h0];
  float cpart = ax * brv.x + ay * brv.y + az * brv.z + aw * brv.w;
  #pragma unroll
  for (int off = 32; off > 0; off >>= 1) cpart += __shfl_down(cpart, off);
  if ((tid & 63) == 0) csum[tid >> 6] = cpart;
  __syncthreads();
  if (tid < 32) {
    if (tid == 0) crow[1536] = f2bf(csum[0] + csum[1] + csum[2] + csum[3]);
    else          crow[1536 + tid] = 0;
  }
}

// ---------------- pipelined GEMM: C[M,N] = A[M,K] @ B[N,K]^T (+bias) ----------------
// 64x64 tile, 4 waves (2x2 of 32x32), BK=32, PD=3 LDS ring, global_load_lds(16B),
// raw vmcnt/barrier pipeline. EPI 0: bf16, EPI 1: f32+bias. Stores guarded by Nmax.
template <int EPI>
__global__ __launch_bounds__(256) void gemm_bt64(
    const short* __restrict__ A, int lda, const short* __restrict__ B, int ldb,
    const float* __restrict__ bias, void* __restrict__ C, int ldc,
    int K, int Nmax) {
  constexpr int PD = 3;
  __shared__ alignas(16) short As[PD][64 * 32];
  __shared__ alignas(16) short Bs[PD][64 * 32];
  const int tid = threadIdx.x;
  const int wave = tid >> 6, lane = tid & 63;
  const int quad = lane >> 4, l16 = lane & 15;
  const int wm = (wave & 1) * 32, wn = (wave >> 1) * 32;
  const int m0 = blockIdx.x * 64, n0 = blockIdx.y * 64;
  const int srow = tid >> 2, scol = (tid & 3) * 8;
  const short* Ag = A + (long)(m0 + srow) * lda + scol;
  const short* Bg = B + (long)(n0 + srow) * ldb + scol;
  const int ldsoff = wave * 16 * 32;  // wave-uniform base (16 rows/wave)
  const int NT = K >> 5;
  auto issue = [&](int kt) {
    int buf = kt % PD; int ko = kt * 32;
    __builtin_amdgcn_global_load_lds((gas_t)(Ag + ko), (las_t)(As[buf] + ldsoff), 16, 0, 0);
    __builtin_amdgcn_global_load_lds((gas_t)(Bg + ko), (las_t)(Bs[buf] + ldsoff), 16, 0, 0);
  };
  f32x4 acc[2][2] = {};
  issue(0); issue(1);
  for (int kt = 0; kt < NT; ++kt) {
    if (kt + 2 < NT) issue(kt + 2);
    int ahead = NT - 1 - kt; if (ahead > 2) ahead = 2;
    if (ahead == 2)      asm volatile("s_waitcnt vmcnt(4)" ::: "memory");
    else if (ahead == 1) asm volatile("s_waitcnt vmcnt(2)" ::: "memory");
    else                 asm volatile("s_waitcnt vmcnt(0)" ::: "memory");
    asm volatile("s_barrier" ::: "memory");
    const short* as = As[kt % PD];
    const short* bs = Bs[kt % PD];
    bf16x8 a0 = *(const bf16x8*)&as[(wm + l16) * 32 + quad * 8];
    bf16x8 a1 = *(const bf16x8*)&as[(wm + 16 + l16) * 32 + quad * 8];
    bf16x8 b0 = *(const bf16x8*)&bs[(wn + l16) * 32 + quad * 8];
    bf16x8 b1 = *(const bf16x8*)&bs[(wn + 16 + l16) * 32 + quad * 8];
    acc[0][0] = __builtin_amdgcn_mfma_f32_16x16x32_bf16(a0, b0, acc[0][0], 0, 0, 0);
    acc[0][1] = __builtin_amdgcn_mfma_f32_16x16x32_bf16(a0, b1, acc[0][1], 0, 0, 0);
    acc[1][0] = __builtin_amdgcn_mfma_f32_16x16x32_bf16(a1, b0, acc[1][0], 0, 0, 0);
    acc[1][1] = __builtin_amdgcn_mfma_f32_16x16x32_bf16(a1, b1, acc[1][1], 0, 0, 0);
    asm volatile("s_barrier" ::: "memory");
  }
  #pragma unroll
  for (int i = 0; i < 2; ++i)
    #pragma unroll
    for (int j = 0; j < 2; ++j) {
      int n = wn + j * 16 + l16;
      if (n0 + n < Nmax) {
        float bc = bias ? bias[n0 + n] : 0.f;
        #pragma unroll
        for (int r = 0; r < 4; ++r) {
          int row = m0 + wm + i * 16 + quad * 4 + r;
          float v = acc[i][j][r] + bc;
          if (EPI == 0) ((short*)C)[(long)row * ldc + n0 + n] = f2bf(v);
          else          ((float*)C)[(long)row * ldc + n0 + n] = v;
        }
      }
    }
}

extern "C" void kernel_launch(void* const* d_in, const int* in_sizes, int n_in,
                              void* d_out, int out_size, void* d_ws, size_t ws_size,
                              hipStream_t stream) {
  const float* ment = (const float*)d_in[0];
  const int*   ents = (const int*)d_in[1];
  const int*   msk  = (const int*)d_in[2];
  const float* rm   = (const float*)d_in[3];
  const float* Wv   = (const float*)d_in[4];
  const float* bv   = (const float*)d_in[5];
  const float* Wu   = (const float*)d_in[6];
  const float* bu   = (const float*)d_in[7];
  const float* Wa   = (const float*)d_in[8];
  // d_in[9] = ba: drops out (softmax shift-invariance; masked slots NEG either way)
  const float* Wr   = (const float*)d_in[10];
  const float* br   = (const float*)d_in[11];
  const float* Wo   = (const float*)d_in[12];
  const float* bo   = (const float*)d_in[13];
  float* out = (float*)d_out;

  char* p = (char*)d_ws;
  auto alloc = [&](size_t bytes) { void* q = (void*)p; p += bytes; return q; };
  short* Xb     = (short*)alloc((size_t)2048 * 1024 * 2);
  short* Wvb    = (short*)alloc((size_t)256 * 1024 * 2);
  short* Wub    = (short*)alloc((size_t)256 * 1024 * 2);
  short* WrTb   = (short*)alloc((size_t)512 * 1024 * 2);
  short* WoFb   = (short*)alloc((size_t)1024 * 1568 * 2);
  short* Wo2b   = (short*)alloc((size_t)1024 * 512 * 2);
  short* rmTaug = (short*)alloc((size_t)576 * 1024 * 2);
  short* Gaugb  = (short*)alloc((size_t)576 * 512 * 2);
  short* catb   = (short*)alloc((size_t)1024 * 1568 * 2);
  float* w      = (float*)alloc((size_t)2048 * 4);

  // 1. casts + transposes + augmentation + zero w
  prep_cast<<<20620, 256, 0, stream>>>(ment, Wv, Wu, Wr, Wo, rm,
                                       Xb, Wvb, Wub, WrTb, WoFb, Wo2b, rmTaug, w);
  // 2. Gaug = [rm^T rm ; g^T] : [576(513),512], K=1024
  gemm_bt64<0><<<dim3(9, 8), 256, 0, stream>>>(rmTaug, 1024, rmTaug, 1024,
                                               nullptr, Gaugb, 512, 1024, 512);
  // 3. GWTaug[h,k] = sum_m Wo2[h,m] Gaug[k,m] -> WoFb cols 1024..1536, K=512
  gemm_bt64<0><<<dim3(16, 9), 256, 0, stream>>>(Wo2b, 512, Gaugb, 512,
                                                nullptr, WoFb + 1024, 1568, 512, 513);
  // 4. gated-MIL logits w (fused gate GEMM + Wa reduce, atomic)
  gemm_vu_w<<<dim3(64, 4), 256, 0, stream>>>(Xb, Wvb, Wub, bv, bu, Wa, w);
  // 5. softmax over K + pooling -> er = catb[:,0:1024], c = catb[:,1536], zeros pad
  softmax_pool<<<1024, 256, 0, stream>>>(ment, ents, msk, w, br, catb);
  // 6. t = er @ Wr -> catb cols 1024..1536, K=1024
  gemm_bt64<0><<<dim3(16, 8), 256, 0, stream>>>(catb, 1568, WrTb, 1024,
                                                nullptr, catb + 1024, 1568, 1024, 512);
  // 7. out = [er|t|c|0] @ [Wo1|GWT|gw2|0]^T + bo : [1024,1024], K=1568, fp32
  gemm_bt64<1><<<dim3(16, 16), 256, 0, stream>>>(catb, 1568, WoFb, 1568,
                                                 bo, out, 1024, 1568, 1024);
}